// Round 5
// baseline (96.554 us; speedup 1.0000x reference)
//
#include <hip/hip_runtime.h>
#include <math.h>

// ---------------- problem constants ----------------
#define P      6400      // SAMPLE*SAMPLE patches per image
#define K      49        // PATCH*PATCH channels (C=1)
#define KP     64        // K padded to MFMA granularity (pad channels are 0)
#define FH     169       // patch-grid H = W = (512-7)/3+1
#define IMG    512
#define EPSF   2.220446049250313e-16f
#define HWT    2.0f      // H_WEIGHT
#define LOCC   0.05f     // LAMBDA_OCC

#define CSPLIT   50                    // column chunks of 128
#define NROWBLK  (P / 32)              // 200 row-blocks (32 rows each)
#define FXSCALE  1099511627776.0       // 2^40 fixed-point scale

typedef __attribute__((ext_vector_type(8))) short bf16x8;  // 8 bf16 = 4 VGPR
typedef __attribute__((ext_vector_type(4))) float f32x4;

__device__ inline unsigned bfbits(float x)   // f32 -> bf16 bits, RNE
{
    unsigned u = __float_as_uint(x);
    return (u + 0x7FFFu + ((u >> 16) & 1u)) >> 16;
}

// ---- shared helpers for the row kernels -----------------------------
// A/B frag: lane l holds 8 contiguous k at row l&15, k0=(l>>4)*8
// C/D:      col=l&15, row=(l>>4)*4+reg
__device__ __forceinline__ void load_b(const unsigned short* __restrict__ rb,
                                       int qc, int w, int l15, int lg,
                                       bf16x8 (&b)[2][2])
{
#pragma unroll
    for (int n = 0; n < 2; ++n) {
        int q = qc * 128 + (w + n * 4) * 16 + l15;
#pragma unroll
        for (int ks = 0; ks < 2; ++ks)
            b[n][ks] = *(const bf16x8*)(rb + q * KP + ks * 32 + lg * 8);
    }
}

__device__ __forceinline__ void load_c(const int* __restrict__ counts,
                                       int qc, int w, int l15, float (&c)[2])
{
#pragma unroll
    for (int n = 0; n < 2; ++n)
        c[n] = (float)counts[qc * 128 + (w + n * 4) * 16 + l15] * LOCC;
}

__device__ __forceinline__ void gemm_chunk(const bf16x8 (&a)[2][2],
                                           const bf16x8 (&b)[2][2],
                                           f32x4 (&acc)[2][2])
{
#pragma unroll
    for (int mt = 0; mt < 2; ++mt)
#pragma unroll
        for (int n = 0; n < 2; ++n) {
            f32x4 c = (f32x4){0.f, 0.f, 0.f, 0.f};
            c = __builtin_amdgcn_mfma_f32_16x16x32_bf16(a[mt][0], b[n][0], c, 0, 0, 0);
            c = __builtin_amdgcn_mfma_f32_16x16x32_bf16(a[mt][1], b[n][1], c, 0, 0, 0);
            acc[mt][n] = c;
        }
}

// =====================================================================
// 1) k_prep: init counts/accum/ticket + refer channel-mean partials
// =====================================================================
__global__ void k_prep(const float* __restrict__ rf, const float* __restrict__ rfield,
                       float* __restrict__ ypart, int* __restrict__ counts,
                       unsigned long long* __restrict__ accum, int* __restrict__ ticket)
{
    int t = threadIdx.x;
    int gid = blockIdx.x * 256 + t;

    if (gid < P) counts[gid] = 0;
    if (gid == 0) { accum[0] = 0ULL; ticket[0] = 0; }

    int c = gid / P;
    int p = gid - c * P;             // block fully inside one c (P % 256 == 0)
    float fx = rfield[p * 2 + 0];
    float fy = rfield[p * 2 + 1];
    float gx = fx * 2.0f - 1.0f;
    float gy = fy * 2.0f - 1.0f;
    int ix = (int)rintf(((gx + 1.0f) * (float)FH - 1.0f) * 0.5f);
    int iy = (int)rintf(((gy + 1.0f) * (float)FH - 1.0f) * 0.5f);
    ix = min(max(ix, 0), FH - 1);
    iy = min(max(iy, 0), FH - 1);
    int ky = c / 7, kx = c - ky * 7;
    float v = rf[(iy * 3 + ky) * IMG + (ix * 3 + kx)];

    float s = v;
#pragma unroll
    for (int m = 1; m < 64; m <<= 1) s += __shfl_xor(s, m, 64);
    __shared__ float acc4[4];
    int l = t & 63, w = t >> 6;
    if (l == 0) acc4[w] = s;
    __syncthreads();
    if (t == 0) ypart[c * 25 + (p >> 8)] = acc4[0] + acc4[1] + acc4[2] + acc4[3];
}

// =====================================================================
// 2) mean-subtract + L2-normalize + pack to bf16, TRANSPOSED [p][64]
// =====================================================================
__global__ void k_normpack(const float* __restrict__ tf, const float* __restrict__ rf,
                           const float* __restrict__ tfield, const float* __restrict__ rfield,
                           const float* __restrict__ ypart,
                           unsigned short* __restrict__ tb, unsigned short* __restrict__ rb)
{
    __shared__ float ym[K];
    int t = threadIdx.x;
    if (t < K) {
        float s = 0.f;
#pragma unroll
        for (int i = 0; i < 25; ++i) s += ypart[t * 25 + i];
        ym[t] = s * (1.0f / (float)P);
    }
    __syncthreads();

    int gid = blockIdx.x * 64 + t;       // grid = 2P/64 = 200 blocks
    int sel = gid >= P;
    int p = sel ? gid - P : gid;
    const float* field = sel ? rfield : tfield;
    const float* feat  = sel ? rf : tf;
    unsigned short* ob = sel ? rb : tb;

    float fx = field[p * 2 + 0];
    float fy = field[p * 2 + 1];
    float gx = fx * 2.0f - 1.0f;
    float gy = fy * 2.0f - 1.0f;
    int ix = (int)rintf(((gx + 1.0f) * (float)FH - 1.0f) * 0.5f);
    int iy = (int)rintf(((gy + 1.0f) * (float)FH - 1.0f) * 0.5f);
    ix = min(max(ix, 0), FH - 1);
    iy = min(max(iy, 0), FH - 1);
    const float* base = feat + (iy * 3) * IMG + ix * 3;

    float v[K];
#pragma unroll
    for (int ky = 0; ky < 7; ++ky)
#pragma unroll
        for (int kx = 0; kx < 7; ++kx)
            v[ky * 7 + kx] = base[ky * IMG + kx];

    float ss = 0.f;
#pragma unroll
    for (int c = 0; c < K; ++c) {
        float x = v[c] - ym[c];
        v[c] = x;
        ss += x * x;
    }
    float rn = 1.0f / (sqrtf(ss) + EPSF);

    unsigned wbuf[KP / 2];
#pragma unroll
    for (int i = 0; i < KP / 2; ++i) {
        int c0 = 2 * i, c1 = 2 * i + 1;
        float x0 = (c0 < K) ? v[c0] * rn : 0.f;
        float x1 = (c1 < K) ? v[c1] * rn : 0.f;
        wbuf[i] = (bfbits(x1) << 16) | bfbits(x0);
    }
    uint4* o = (uint4*)(ob + p * KP);
#pragma unroll
    for (int i = 0; i < KP / 8; ++i)
        o[i] = make_uint4(wbuf[4 * i], wbuf[4 * i + 1], wbuf[4 * i + 2], wbuf[4 * i + 3]);
}

// =====================================================================
// 3) k_rowmin: 200 blocks x 32 rows; each wave scans ALL 6400 cols for
//    its q-subset (q%128 in wave's two 16-col tiles). B read straight
//    from L2 (fully coalesced, rb is L2-resident) -- no LDS staging, no
//    barriers in the main loop. Per-row argmin of d0 finishes IN-BLOCK
//    (u64 lex-min: first-occurrence ties); tail = 32 atomicAdd(counts)
//    -> the histogram kernel disappears (O(32) tail, not O(P)!).
// =====================================================================
__global__ void k_rowmin(const unsigned short* __restrict__ tb,
                         const unsigned short* __restrict__ rb,
                         int* __restrict__ counts)
{
    const int p0 = blockIdx.x * 32;
    const int t  = threadIdx.x;
    const int w  = t >> 6, l = t & 63;
    const int l15 = l & 15, lg = l >> 4;

    bf16x8 afr[2][2];
#pragma unroll
    for (int mt = 0; mt < 2; ++mt)
#pragma unroll
        for (int ks = 0; ks < 2; ++ks)
            afr[mt][ks] = *(const bf16x8*)(tb + (p0 + mt * 16 + l15) * KP + ks * 32 + lg * 8);

    unsigned long long enc[2][4];
#pragma unroll
    for (int mt = 0; mt < 2; ++mt)
#pragma unroll
        for (int r = 0; r < 4; ++r) enc[mt][r] = 0xFFFFFFFFFFFFFFFFULL;

    bf16x8 bf0[2][2], bf1[2][2];
    load_b(rb, 0, w, l15, lg, bf0);
    for (int qc = 0; qc < CSPLIT; ++qc) {
        if (qc + 1 < CSPLIT) load_b(rb, qc + 1, w, l15, lg, bf1);
        f32x4 acc[2][2];
        gemm_chunk(afr, bf0, acc);
        const int qa = qc * 128 + w * 16 + l15;    // nt'=0 col; nt'=1 is +64
#pragma unroll
        for (int mt = 0; mt < 2; ++mt)
#pragma unroll
            for (int r = 0; r < 4; ++r) {
                float d0 = fmaxf((1.0f - acc[mt][0][r]) * 0.5f, 0.0f);
                float d1 = fmaxf((1.0f - acc[mt][1][r]) * 0.5f, 0.0f);
                bool sw = d1 < d0;                  // strict: tie -> lower q
                float dm = sw ? d1 : d0;
                unsigned qi = (unsigned)(sw ? qa + 64 : qa);
                unsigned long long e =
                    ((unsigned long long)__float_as_uint(dm) << 32) | qi;
                enc[mt][r] = e < enc[mt][r] ? e : enc[mt][r];
            }
#pragma unroll
        for (int n = 0; n < 2; ++n)
#pragma unroll
            for (int ks = 0; ks < 2; ++ks) bf0[n][ks] = bf1[n][ks];
    }

    __shared__ unsigned long long wminU[4][32];
#pragma unroll
    for (int mt = 0; mt < 2; ++mt)
#pragma unroll
        for (int r = 0; r < 4; ++r) {
            unsigned long long e = enc[mt][r];
#pragma unroll
            for (int m = 1; m < 16; m <<= 1) {
                unsigned long long o = __shfl_xor(e, m, 64);
                e = o < e ? o : e;
            }
            if (l15 == 0) wminU[w][mt * 16 + lg * 4 + r] = e;
        }
    __syncthreads();
    if (t < 32) {
        unsigned long long e = wminU[0][t];
        e = wminU[1][t] < e ? wminU[1][t] : e;
        e = wminU[2][t] < e ? wminU[2][t] : e;
        e = wminU[3][t] < e ? wminU[3][t] : e;
        atomicAdd(&counts[(unsigned)(e & 0xffffffffu)], 1);
    }
}

// =====================================================================
// 4) k_sweep23: fused MODE2+MODE3+loss. Same row geometry as k_rowmin.
//    pass 1: row-min of (d0 + counts[q]*LOCC) -> registers/LDS (no mbits
//            global round-trip)
//    pass 2: recompute GEMM, accumulate exp((1 - d/(dmin+EPS))*HWT)
//    tail:   per-row v = log(s) - lw, block partial (fixed order),
//            exact fixed-point atomicAdd + O(1) ticket tail writes out.
// =====================================================================
__global__ void k_sweep23(const unsigned short* __restrict__ tb,
                          const unsigned short* __restrict__ rb,
                          const int* __restrict__ counts,
                          unsigned long long* __restrict__ accum,
                          int* __restrict__ ticket,
                          float* __restrict__ out)
{
    const int p0 = blockIdx.x * 32;
    const int t  = threadIdx.x;
    const int w  = t >> 6, l = t & 63;
    const int l15 = l & 15, lg = l >> 4;

    __shared__ float wred[4][32];
    __shared__ float dminS[32];
    __shared__ float vv[32];

    bf16x8 afr[2][2];
#pragma unroll
    for (int mt = 0; mt < 2; ++mt)
#pragma unroll
        for (int ks = 0; ks < 2; ++ks)
            afr[mt][ks] = *(const bf16x8*)(tb + (p0 + mt * 16 + l15) * KP + ks * 32 + lg * 8);

    // ---------------- pass 1: occur-adjusted row min ----------------
    float bv[2][4];
#pragma unroll
    for (int mt = 0; mt < 2; ++mt)
#pragma unroll
        for (int r = 0; r < 4; ++r) bv[mt][r] = 1e30f;

    {
        bf16x8 bf0[2][2], bf1[2][2]; float c0[2], c1[2];
        load_b(rb, 0, w, l15, lg, bf0); load_c(counts, 0, w, l15, c0);
        for (int qc = 0; qc < CSPLIT; ++qc) {
            if (qc + 1 < CSPLIT) {
                load_b(rb, qc + 1, w, l15, lg, bf1);
                load_c(counts, qc + 1, w, l15, c1);
            }
            f32x4 acc[2][2];
            gemm_chunk(afr, bf0, acc);
#pragma unroll
            for (int mt = 0; mt < 2; ++mt)
#pragma unroll
                for (int r = 0; r < 4; ++r) {
                    float d0 = fmaxf((1.0f - acc[mt][0][r]) * 0.5f, 0.0f) + c0[0];
                    float d1 = fmaxf((1.0f - acc[mt][1][r]) * 0.5f, 0.0f) + c0[1];
                    bv[mt][r] = fminf(bv[mt][r], fminf(d0, d1));
                }
#pragma unroll
            for (int n = 0; n < 2; ++n)
#pragma unroll
                for (int ks = 0; ks < 2; ++ks) bf0[n][ks] = bf1[n][ks];
            c0[0] = c1[0]; c0[1] = c1[1];
        }
    }

#pragma unroll
    for (int mt = 0; mt < 2; ++mt)
#pragma unroll
        for (int r = 0; r < 4; ++r) {
            float e = bv[mt][r];
#pragma unroll
            for (int m = 1; m < 16; m <<= 1) e = fminf(e, __shfl_xor(e, m, 64));
            if (l15 == 0) wred[w][mt * 16 + lg * 4 + r] = e;
        }
    __syncthreads();
    if (t < 32)
        dminS[t] = fminf(fminf(wred[0][t], wred[1][t]), fminf(wred[2][t], wred[3][t]));
    __syncthreads();

    float rv[2][4], sacc[2][4];
#pragma unroll
    for (int mt = 0; mt < 2; ++mt)
#pragma unroll
        for (int r = 0; r < 4; ++r) {
            rv[mt][r] = 1.0f / (dminS[mt * 16 + lg * 4 + r] + EPSF);
            sacc[mt][r] = 0.f;
        }

    // ---------------- pass 2: exp sums ----------------
    {
        bf16x8 bf0[2][2], bf1[2][2]; float c0[2], c1[2];
        load_b(rb, 0, w, l15, lg, bf0); load_c(counts, 0, w, l15, c0);
        for (int qc = 0; qc < CSPLIT; ++qc) {
            if (qc + 1 < CSPLIT) {
                load_b(rb, qc + 1, w, l15, lg, bf1);
                load_c(counts, qc + 1, w, l15, c1);
            }
            f32x4 acc[2][2];
            gemm_chunk(afr, bf0, acc);
#pragma unroll
            for (int mt = 0; mt < 2; ++mt)
#pragma unroll
                for (int r = 0; r < 4; ++r) {
                    float d0 = fmaxf((1.0f - acc[mt][0][r]) * 0.5f, 0.0f) + c0[0];
                    float d1 = fmaxf((1.0f - acc[mt][1][r]) * 0.5f, 0.0f) + c0[1];
                    sacc[mt][r] += __expf((1.0f - d0 * rv[mt][r]) * HWT)
                                 + __expf((1.0f - d1 * rv[mt][r]) * HWT);
                }
#pragma unroll
            for (int n = 0; n < 2; ++n)
#pragma unroll
                for (int ks = 0; ks < 2; ++ks) bf0[n][ks] = bf1[n][ks];
            c0[0] = c1[0]; c0[1] = c1[1];
        }
    }

#pragma unroll
    for (int mt = 0; mt < 2; ++mt)
#pragma unroll
        for (int r = 0; r < 4; ++r) {
            float e = sacc[mt][r];
#pragma unroll
            for (int m = 1; m < 16; m <<= 1) e += __shfl_xor(e, m, 64);
            if (l15 == 0) wred[w][mt * 16 + lg * 4 + r] = e;
        }
    __syncthreads();

    // ---------------- tail: per-row loss, block partial, O(1) finish ----
    if (t < 32) {
        float s = ((wred[0][t] + wred[1][t]) + wred[2][t]) + wred[3][t];
        float m = dminS[t];
        float lw = (1.0f - m / (m + EPSF)) * HWT;
        vv[t] = logf(s) - lw;
    }
    __syncthreads();
    if (t == 0) {
        float vsum = 0.f;
#pragma unroll
        for (int i = 0; i < 32; ++i) vsum += vv[i];
        double sd = (double)vsum * FXSCALE;
        long long fx = (long long)(sd + (sd >= 0.0 ? 0.5 : -0.5));
        atomicAdd(accum, (unsigned long long)fx);
        asm volatile("s_waitcnt vmcnt(0)" ::: "memory");   // accum add performed
        int tk = atomicAdd(ticket, 1);
        if (tk == NROWBLK - 1) {
            unsigned long long tot = atomicAdd(accum, 0ULL);  // coherent read
            out[0] = (float)((double)(long long)tot * (1.0 / FXSCALE) / (double)P);
        }
    }
}

// =====================================================================
extern "C" void kernel_launch(void* const* d_in, const int* in_sizes, int n_in,
                              void* d_out, int out_size, void* d_ws, size_t ws_size,
                              hipStream_t stream)
{
    const float* tf  = (const float*)d_in[0];
    const float* rf  = (const float*)d_in[1];
    const float* tfd = (const float*)d_in[2];
    const float* rfd = (const float*)d_in[3];
    float* out = (float*)d_out;

    float* ws = (float*)d_ws;
    float* ypart = ws;                                       // K*25 = 1225 f
    unsigned short* tb = (unsigned short*)(ws + 2048);       // P*KP bf16 = 204800 f
    unsigned short* rb = (unsigned short*)(ws + 206848);     // P*KP bf16 = 204800 f
    int* counts = (int*)(ws + 411648);                       // P ints
    unsigned long long* accum = (unsigned long long*)(ws + 418048); // 8B aligned
    int* ticket = (int*)(ws + 418050);                       // 1
    // total ~418051 floats ~= 1.67 MB

    // 4 kernels: prep | normpack | rowmin(+counts) | sweep23(+loss)
    k_prep<<<K * P / 256, 256, 0, stream>>>(rf, rfd, ypart, counts, accum, ticket);
    k_normpack<<<2 * P / 64, 64, 0, stream>>>(tf, rf, tfd, rfd, ypart, tb, rb);
    k_rowmin<<<NROWBLK, 256, 0, stream>>>(tb, rb, counts);
    k_sweep23<<<NROWBLK, 256, 0, stream>>>(tb, rb, counts, accum, ticket, out);
}

// Round 6
// 78.397 us; speedup vs baseline: 1.2316x; 1.2316x over previous
//
#include <hip/hip_runtime.h>
#include <math.h>

// ---------------- problem constants ----------------
#define P      6400      // SAMPLE*SAMPLE patches per image
#define K      49        // PATCH*PATCH channels (C=1)
#define KP     64        // K padded to MFMA granularity (pad channels are 0)
#define FH     169       // patch-grid H = W = (512-7)/3+1
#define IMG    512
#define EPSF   2.220446049250313e-16f
#define HWT    2.0f      // H_WEIGHT
#define LOCC   0.05f     // LAMBDA_OCC

// ---------------- sweep tiling ----------------
#define CSPLIT 50
#define QCHUNK  (P / CSPLIT)          // 128 columns per block
#define NROWGRP (P / 128)             // 50 row groups of 128 rows
#define FXSCALE 1099511627776.0       // 2^40 fixed-point scale

typedef __attribute__((ext_vector_type(8))) short bf16x8;  // 8 bf16 = 4 VGPR
typedef __attribute__((ext_vector_type(4))) float f32x4;

__device__ inline unsigned bfbits(float x)   // f32 -> bf16 bits, RNE
{
    unsigned u = __float_as_uint(x);
    return (u + 0x7FFFu + ((u >> 16) & 1u)) >> 16;
}

// =====================================================================
// 1) k_prep: init atomic buffers/tickets + refer channel-mean partials
//    grid = K*P/256 = 1225 blocks; each block lies in one c slice.
// =====================================================================
__global__ void k_prep(const float* __restrict__ rf, const float* __restrict__ rfield,
                       float* __restrict__ ypart,
                       unsigned long long* __restrict__ packed1,
                       int* __restrict__ counts, unsigned* __restrict__ mbits,
                       unsigned long long* __restrict__ Ssum,
                       int* __restrict__ rt1, int* __restrict__ rt3,
                       int* __restrict__ ticket2, unsigned long long* __restrict__ accum)
{
    int t = threadIdx.x;
    int gid = blockIdx.x * 256 + t;

    if (gid < P) {
        packed1[gid] = 0xFFFFFFFFFFFFFFFFULL;
        counts[gid]  = 0;
        mbits[gid]   = 0xFFFFFFFFu;
        Ssum[gid]    = 0ULL;
    }
    if (gid < NROWGRP) { rt1[gid] = 0; rt3[gid] = 0; }
    if (gid == 0) { ticket2[0] = 0; accum[0] = 0ULL; }

    // ---- refer channel-mean partials
    int c = gid / P;
    int p = gid - c * P;             // block fully inside one c (P % 256 == 0)
    float fx = rfield[p * 2 + 0];
    float fy = rfield[p * 2 + 1];
    float gx = fx * 2.0f - 1.0f;
    float gy = fy * 2.0f - 1.0f;
    int ix = (int)rintf(((gx + 1.0f) * (float)FH - 1.0f) * 0.5f);
    int iy = (int)rintf(((gy + 1.0f) * (float)FH - 1.0f) * 0.5f);
    ix = min(max(ix, 0), FH - 1);
    iy = min(max(iy, 0), FH - 1);
    int ky = c / 7, kx = c - ky * 7;
    float v = rf[(iy * 3 + ky) * IMG + (ix * 3 + kx)];

    float s = v;
#pragma unroll
    for (int m = 1; m < 64; m <<= 1) s += __shfl_xor(s, m, 64);
    __shared__ float acc4[4];
    int l = t & 63, w = t >> 6;
    if (l == 0) acc4[w] = s;
    __syncthreads();
    if (t == 0) ypart[c * 25 + (p >> 8)] = acc4[0] + acc4[1] + acc4[2] + acc4[3];
}

// =====================================================================
// 2) mean-subtract + L2-normalize + pack to bf16, TRANSPOSED [p][64]
//    Gathers the 49 patch values straight from the image into registers.
//    64-thread blocks x 200: scatter-latency-bound -> spread across CUs.
// =====================================================================
__global__ void k_normpack(const float* __restrict__ tf, const float* __restrict__ rf,
                           const float* __restrict__ tfield, const float* __restrict__ rfield,
                           const float* __restrict__ ypart,
                           unsigned short* __restrict__ tb, unsigned short* __restrict__ rb)
{
    __shared__ float ym[K];
    int t = threadIdx.x;
    if (t < K) {
        float s = 0.f;
#pragma unroll
        for (int i = 0; i < 25; ++i) s += ypart[t * 25 + i];
        ym[t] = s * (1.0f / (float)P);
    }
    __syncthreads();

    int gid = blockIdx.x * 64 + t;       // grid = 2P/64 = 200 blocks
    int sel = gid >= P;
    int p = sel ? gid - P : gid;
    const float* field = sel ? rfield : tfield;
    const float* feat  = sel ? rf : tf;
    unsigned short* ob = sel ? rb : tb;

    float fx = field[p * 2 + 0];
    float fy = field[p * 2 + 1];
    float gx = fx * 2.0f - 1.0f;
    float gy = fy * 2.0f - 1.0f;
    int ix = (int)rintf(((gx + 1.0f) * (float)FH - 1.0f) * 0.5f);
    int iy = (int)rintf(((gy + 1.0f) * (float)FH - 1.0f) * 0.5f);
    ix = min(max(ix, 0), FH - 1);
    iy = min(max(iy, 0), FH - 1);
    const float* base = feat + (iy * 3) * IMG + ix * 3;

    float v[K];
#pragma unroll
    for (int ky = 0; ky < 7; ++ky)
#pragma unroll
        for (int kx = 0; kx < 7; ++kx)
            v[ky * 7 + kx] = base[ky * IMG + kx];

    float ss = 0.f;
#pragma unroll
    for (int c = 0; c < K; ++c) {
        float x = v[c] - ym[c];
        v[c] = x;
        ss += x * x;
    }
    float rn = 1.0f / (sqrtf(ss) + EPSF);

    unsigned wbuf[KP / 2];
#pragma unroll
    for (int i = 0; i < KP / 2; ++i) {
        int c0 = 2 * i, c1 = 2 * i + 1;
        float x0 = (c0 < K) ? v[c0] * rn : 0.f;
        float x1 = (c1 < K) ? v[c1] * rn : 0.f;
        wbuf[i] = (bfbits(x1) << 16) | bfbits(x0);
    }
    uint4* o = (uint4*)(ob + p * KP);
#pragma unroll
    for (int i = 0; i < KP / 8; ++i)
        o[i] = make_uint4(wbuf[4 * i], wbuf[4 * i + 1], wbuf[4 * i + 2], wbuf[4 * i + 3]);
}

// =====================================================================
// 3) MFMA sim sweeps (R2 geometry: 4 waves; 128(p) x 128(q); K=64).
//    B tile staged once in LDS, XOR-swizzled 16B chunks (conflict-free).
//    A/B frag: lane l holds 8 contiguous k at row l&15, k0=(l>>4)*8
//    C/D:      col=l&15, row=(l>>4)*4+reg
//
//    MODE 1: per-row argmin of d0 -> atomicMin u64 packed1.
//            TAIL: per-ROW-GROUP ticket; 50th chunk-block for a row group
//            (happens-before on all its atomicMins via the barrier drain)
//            reads the 128 final packed1 and scatters atomicAdd(counts).
//            O(128) per finisher, 50 finishers in parallel -- unlike
//            R3 (O(P) serial tail) and R4 (O(P) per-block scans).
//    MODE 2: per-row min of d0 + counts[q]*LOCC -> atomicMin u32 mbits.
//    MODE 3: per-row sum exp((1-d/(m+EPS))*H) -> exact fixed-point
//            atomicAdd(Ssum).  TAIL: row-group ticket; finisher computes
//            the 128 logs (mbits final since sweep2's boundary), fixed-
//            order reduce, signed fixed-point atomicAdd(accum); last of
//            50 finishers (vmcnt-ordered ticket) writes out.
//    Zero wave-wide fences anywhere (R1 lesson).
// =====================================================================
template<int MODE>
__global__ __launch_bounds__(256, 4)
void k_sweep(const unsigned short* __restrict__ tb, const unsigned short* __restrict__ rb,
             int* __restrict__ counts, unsigned* __restrict__ mbits,
             unsigned long long* __restrict__ packed1,
             unsigned long long* __restrict__ Ssum,
             int* __restrict__ rowtick, int* __restrict__ ticket2,
             unsigned long long* __restrict__ accum, float* __restrict__ out)
{
    __shared__ uint4 bs[1024];           // 16 KB: 128 rows x 8 chunks of 16B
    const int p0 = blockIdx.x * 128, q0 = blockIdx.y * QCHUNK;
    const int t  = threadIdx.x;
    const int w  = t >> 6, l = t & 63;
    const int l15 = l & 15, lg = l >> 4;

    // A fragments: issue global loads first so they overlap the staging
    bf16x8 afr[2][2];
#pragma unroll
    for (int mt = 0; mt < 2; ++mt)
#pragma unroll
        for (int ks = 0; ks < 2; ++ks)
            afr[mt][ks] = *(const bf16x8*)(tb + (p0 + w * 32 + mt * 16 + l15) * KP + ks * 32 + lg * 8);

    // ---- stage B tile: 1024 16B chunks; 4 per thread, XOR-swizzled write
    {
        const int r = t >> 1;            // 2 threads per row, 4 chunks each
        const int cbase = (t & 1) * 4;
        const uint4* src = (const uint4*)(rb + (q0 + r) * KP);
#pragma unroll
        for (int i = 0; i < 4; ++i) {
            int c = cbase + i;
            bs[r * 8 + (c ^ (r & 7))] = src[c];
        }
    }
    __syncthreads();

    f32x4 acc[2][8];
#pragma unroll
    for (int mt = 0; mt < 2; ++mt)
#pragma unroll
        for (int qt = 0; qt < 8; ++qt) acc[mt][qt] = (f32x4){0.f, 0.f, 0.f, 0.f};

#pragma unroll
    for (int qt = 0; qt < 8; ++qt) {
        const int row = qt * 16 + l15;
        bf16x8 b0 = *(const bf16x8*)&bs[row * 8 + ((0 + lg) ^ (row & 7))];
        bf16x8 b1 = *(const bf16x8*)&bs[row * 8 + ((4 + lg) ^ (row & 7))];
#pragma unroll
        for (int mt = 0; mt < 2; ++mt) {
            acc[mt][qt] = __builtin_amdgcn_mfma_f32_16x16x32_bf16(afr[mt][0], b0, acc[mt][qt], 0, 0, 0);
            acc[mt][qt] = __builtin_amdgcn_mfma_f32_16x16x32_bf16(afr[mt][1], b1, acc[mt][qt], 0, 0, 0);
        }
    }

    float osv[8];
    if (MODE >= 2) {
#pragma unroll
        for (int qt = 0; qt < 8; ++qt) osv[qt] = (float)counts[q0 + qt * 16 + l15] * LOCC;
    }

#pragma unroll
    for (int mt = 0; mt < 2; ++mt) {
#pragma unroll
        for (int r = 0; r < 4; ++r) {
            int p = p0 + w * 32 + mt * 16 + lg * 4 + r;
            float rinv = 0.f;
            if (MODE == 3) rinv = 1.0f / (__uint_as_float(mbits[p]) + EPSF);

            float bv = 1e30f; int bi = 0; float s = 0.f;
#pragma unroll
            for (int qt = 0; qt < 8; ++qt) {    // qt ascending -> q ascending per lane
                float d = fmaxf((1.0f - acc[mt][qt][r]) * 0.5f, 0.0f);
                if (MODE >= 2) d += osv[qt];
                if (MODE == 1) {
                    bool upd = d < bv;          // strict <: first occurrence wins
                    bi = upd ? (q0 + qt * 16 + l15) : bi;
                    bv = upd ? d : bv;
                } else if (MODE == 2) {
                    bv = fminf(bv, d);
                } else {
                    s += __expf((1.0f - d * rinv) * HWT);
                }
            }

            if (MODE == 1) {
                // packed (value,index) lexicographic min: d >= 0 so f32 bits
                // are order-preserving; ties -> smaller q.
                unsigned long long enc =
                    ((unsigned long long)__float_as_uint(bv) << 32) | (unsigned)bi;
#pragma unroll
                for (int m = 1; m < 16; m <<= 1) {
                    unsigned long long o = __shfl_xor(enc, m, 64);
                    enc = (o < enc) ? o : enc;
                }
                if (l15 == 0) atomicMin(&packed1[p], enc);
            } else if (MODE == 2) {
#pragma unroll
                for (int m = 1; m < 16; m <<= 1) bv = fminf(bv, __shfl_xor(bv, m, 64));
                if (l15 == 0) atomicMin(&mbits[p], __float_as_uint(bv));
            } else {
#pragma unroll
                for (int m = 1; m < 16; m <<= 1) s += __shfl_xor(s, m, 64);
                if (l15 == 0) {
                    // exact: (double)s * 2^40 is exact (s <= 128 -> < 2^47)
                    double sd = (double)s * FXSCALE + 0.5;
                    atomicAdd(&Ssum[p], (unsigned long long)sd);
                }
            }
        }
    }

    // ---- MODE 1 tail: distributed histogram via row-group finisher ----
    if (MODE == 1) {
        __syncthreads();                 // barrier drain -> block's atomicMins performed
        __shared__ int fin1;
        if (t == 0) fin1 = (atomicAdd(&rowtick[blockIdx.x], 1) == CSPLIT - 1);
        __syncthreads();
        if (fin1 && t < 128) {
            unsigned long long v = atomicAdd(&packed1[p0 + t], 0ULL);  // coherent read
            atomicAdd(&counts[(unsigned)(v & 0xffffffffULL)], 1);
        }
    }

    // ---- MODE 3 tail: distributed loss via row-group finisher ----
    if (MODE == 3) {
        __syncthreads();                 // barrier drain -> block's Ssum adds performed
        __shared__ int fin3;
        __shared__ float red[128];
        if (t == 0) fin3 = (atomicAdd(&rowtick[blockIdx.x], 1) == CSPLIT - 1);
        __syncthreads();
        if (fin3) {                      // block-uniform branch
            float v = 0.f;
            if (t < 128) {
                int p = p0 + t;
                unsigned long long sv = atomicAdd(&Ssum[p], 0ULL);     // final (50 tickets)
                float sf = (float)((double)sv * (1.0 / FXSCALE));
                float m = __uint_as_float(mbits[p]);  // final since sweep2 boundary
                float lw = (1.0f - m / (m + EPSF)) * HWT;
                v = logf(sf) - lw;
                red[t] = v;
            }
            __syncthreads();
            for (int ww = 64; ww > 0; ww >>= 1) {
                if (t < ww && t + ww < 128) red[t] += red[t + ww];
                __syncthreads();
            }
            if (t == 0) {
                double sd = (double)red[0] * FXSCALE;
                long long fx = (long long)(sd + (sd >= 0.0 ? 0.5 : -0.5));
                atomicAdd(accum, (unsigned long long)fx);   // signed via 2's complement
                asm volatile("s_waitcnt vmcnt(0)" ::: "memory");  // order before ticket
                int g = atomicAdd(ticket2, 1);
                if (g == NROWGRP - 1) {
                    unsigned long long tot = atomicAdd(accum, 0ULL);  // coherent read
                    out[0] = (float)((double)(long long)tot * (1.0 / FXSCALE) / (double)P);
                }
            }
        }
    }
}

// =====================================================================
extern "C" void kernel_launch(void* const* d_in, const int* in_sizes, int n_in,
                              void* d_out, int out_size, void* d_ws, size_t ws_size,
                              hipStream_t stream)
{
    const float* tf  = (const float*)d_in[0];
    const float* rf  = (const float*)d_in[1];
    const float* tfd = (const float*)d_in[2];
    const float* rfd = (const float*)d_in[3];
    float* out = (float*)d_out;

    float* ws = (float*)d_ws;
    float* ypart = ws;                                       // K*25 = 1225 f
    unsigned short* tb = (unsigned short*)(ws + 2048);       // P*KP bf16 = 204800 f
    unsigned short* rb = (unsigned short*)(ws + 206848);     // P*KP bf16 = 204800 f
    unsigned long long* packed1 = (unsigned long long*)(ws + 411648); // P u64 = 12800 f
    unsigned long long* Ssum    = (unsigned long long*)(ws + 424448); // P u64 = 12800 f
    unsigned* mbits = (unsigned*)(ws + 437248);              // P
    int* counts     = (int*)(ws + 443648);                   // P
    int* rt1        = (int*)(ws + 450048);                   // 50
    int* rt3        = (int*)(ws + 450112);                   // 50
    int* ticket2    = (int*)(ws + 450176);                   // 1
    unsigned long long* accum = (unsigned long long*)(ws + 450178); // 8B-aligned (even off)
    // total ~450180 floats ~= 1.8 MB

    // 5 kernels: prep | normpack | sweep1(+hist tail) | sweep2 | sweep3(+loss tail)
    k_prep<<<K * P / 256, 256, 0, stream>>>(rf, rfd, ypart, packed1, counts, mbits, Ssum,
                                            rt1, rt3, ticket2, accum);
    k_normpack<<<2 * P / 64, 64, 0, stream>>>(tf, rf, tfd, rfd, ypart, tb, rb);

    dim3 g(NROWGRP, CSPLIT);
    k_sweep<1><<<g, 256, 0, stream>>>(tb, rb, counts, mbits, packed1, Ssum, rt1,
                                      nullptr, nullptr, nullptr);
    k_sweep<2><<<g, 256, 0, stream>>>(tb, rb, counts, mbits, packed1, Ssum, nullptr,
                                      nullptr, nullptr, nullptr);
    k_sweep<3><<<g, 256, 0, stream>>>(tb, rb, counts, mbits, packed1, Ssum, rt3,
                                      ticket2, accum, out);
}

// Round 7
// 73.784 us; speedup vs baseline: 1.3086x; 1.0625x over previous
//
#include <hip/hip_runtime.h>
#include <math.h>

// ---------------- problem constants ----------------
#define P      6400      // SAMPLE*SAMPLE patches per image
#define K      49        // PATCH*PATCH channels (C=1)
#define KP     64        // K padded to MFMA granularity (pad channels are 0)
#define FH     169       // patch-grid H = W = (512-7)/3+1
#define IMG    512
#define EPSF   2.220446049250313e-16f
#define HWT    2.0f      // H_WEIGHT
#define LOCC   0.05f     // LAMBDA_OCC

// ---------------- sweep tiling ----------------
#define CSPLIT 50
#define QCHUNK  (P / CSPLIT)          // 128 columns per block
#define RROWS   256                   // rows per block (8 waves x 32)
#define FXSCALE 1099511627776.0       // 2^40 fixed-point scale

typedef __attribute__((ext_vector_type(8))) short bf16x8;  // 8 bf16 = 4 VGPR
typedef __attribute__((ext_vector_type(4))) float f32x4;

__device__ inline unsigned bfbits(float x)   // f32 -> bf16 bits, RNE
{
    unsigned u = __float_as_uint(x);
    return (u + 0x7FFFu + ((u >> 16) & 1u)) >> 16;
}

// =====================================================================
// 1) k_prep: init atomic buffers + ticket + refer channel-mean partials
//    grid = K*P/256 = 1225 blocks; each block lies in one c slice.
// =====================================================================
__global__ void k_prep(const float* __restrict__ rf, const float* __restrict__ rfield,
                       float* __restrict__ ypart,
                       unsigned long long* __restrict__ packed1,
                       int* __restrict__ counts, unsigned* __restrict__ mbits,
                       unsigned long long* __restrict__ Ssum,
                       int* __restrict__ ticket)
{
    int t = threadIdx.x;
    int gid = blockIdx.x * 256 + t;

    if (gid < P) {
        packed1[gid] = 0xFFFFFFFFFFFFFFFFULL;
        counts[gid]  = 0;
        mbits[gid]   = 0xFFFFFFFFu;
        Ssum[gid]    = 0ULL;
    }
    if (gid == 0) ticket[0] = 0;

    // ---- refer channel-mean partials
    int c = gid / P;
    int p = gid - c * P;             // block fully inside one c (P % 256 == 0)
    float fx = rfield[p * 2 + 0];
    float fy = rfield[p * 2 + 1];
    float gx = fx * 2.0f - 1.0f;
    float gy = fy * 2.0f - 1.0f;
    int ix = (int)rintf(((gx + 1.0f) * (float)FH - 1.0f) * 0.5f);
    int iy = (int)rintf(((gy + 1.0f) * (float)FH - 1.0f) * 0.5f);
    ix = min(max(ix, 0), FH - 1);
    iy = min(max(iy, 0), FH - 1);
    int ky = c / 7, kx = c - ky * 7;
    float v = rf[(iy * 3 + ky) * IMG + (ix * 3 + kx)];

    float s = v;
#pragma unroll
    for (int m = 1; m < 64; m <<= 1) s += __shfl_xor(s, m, 64);
    __shared__ float acc4[4];
    int l = t & 63, w = t >> 6;
    if (l == 0) acc4[w] = s;
    __syncthreads();
    if (t == 0) ypart[c * 25 + (p >> 8)] = acc4[0] + acc4[1] + acc4[2] + acc4[3];
}

// =====================================================================
// 2) mean-subtract + L2-normalize + pack to bf16, TRANSPOSED [p][64]
//    (R2-verbatim: 256-thread blocks, direct image gather)
// =====================================================================
__global__ void k_normpack(const float* __restrict__ tf, const float* __restrict__ rf,
                           const float* __restrict__ tfield, const float* __restrict__ rfield,
                           const float* __restrict__ ypart,
                           unsigned short* __restrict__ tb, unsigned short* __restrict__ rb)
{
    __shared__ float ym[K];
    int t = threadIdx.x;
    if (t < K) {
        float s = 0.f;
#pragma unroll
        for (int i = 0; i < 25; ++i) s += ypart[t * 25 + i];
        ym[t] = s * (1.0f / (float)P);
    }
    __syncthreads();

    int gid = blockIdx.x * 256 + t;      // grid = 2P/256 = 50 blocks
    int sel = gid >= P;
    int p = sel ? gid - P : gid;
    const float* field = sel ? rfield : tfield;
    const float* feat  = sel ? rf : tf;
    unsigned short* ob = sel ? rb : tb;

    float fx = field[p * 2 + 0];
    float fy = field[p * 2 + 1];
    float gx = fx * 2.0f - 1.0f;
    float gy = fy * 2.0f - 1.0f;
    int ix = (int)rintf(((gx + 1.0f) * (float)FH - 1.0f) * 0.5f);
    int iy = (int)rintf(((gy + 1.0f) * (float)FH - 1.0f) * 0.5f);
    ix = min(max(ix, 0), FH - 1);
    iy = min(max(iy, 0), FH - 1);
    const float* base = feat + (iy * 3) * IMG + ix * 3;

    float v[K];
#pragma unroll
    for (int ky = 0; ky < 7; ++ky)
#pragma unroll
        for (int kx = 0; kx < 7; ++kx)
            v[ky * 7 + kx] = base[ky * IMG + kx];

    float ss = 0.f;
#pragma unroll
    for (int c = 0; c < K; ++c) {
        float x = v[c] - ym[c];
        v[c] = x;
        ss += x * x;
    }
    float rn = 1.0f / (sqrtf(ss) + EPSF);

    unsigned wbuf[KP / 2];
#pragma unroll
    for (int i = 0; i < KP / 2; ++i) {
        int c0 = 2 * i, c1 = 2 * i + 1;
        float x0 = (c0 < K) ? v[c0] * rn : 0.f;
        float x1 = (c1 < K) ? v[c1] * rn : 0.f;
        wbuf[i] = (bfbits(x1) << 16) | bfbits(x0);
    }
    uint4* o = (uint4*)(ob + p * KP);    // p*128 bytes: 16B aligned
#pragma unroll
    for (int i = 0; i < KP / 8; ++i)
        o[i] = make_uint4(wbuf[4 * i], wbuf[4 * i + 1], wbuf[4 * i + 2], wbuf[4 * i + 3]);
}

// =====================================================================
// 3) MFMA sim sweeps. 8 waves; 256(p) x 128(q) tile; K=64 (2 steps).
//    Per-wave code identical to the proven R2 kernel (wave owns a 32x128
//    strip); 8 waves share one staged B tile -> staging events and B L2
//    traffic halve vs the 4-wave version. B tile XOR-swizzled in 16B
//    chunks (conflict-free, measured 0 conflicts in R2).
//    A/B frag: lane l holds 8 contiguous k at row l&15, k0=(l>>4)*8
//    C/D:      col=l&15, row=(l>>4)*4+reg
//    MODE 1: per-row argmin of d0 (first-occurrence ties) -> atomicMin u64
//    MODE 2: per-row min of d0 + counts[q]*LOCC           -> atomicMin u32
//    MODE 3: per-row sum exp((1-d/(m+EPS))*H) -> exact fixed-point
//            atomicAdd(Ssum)  (integer adds commute -> deterministic)
// =====================================================================
template<int MODE>
__global__ __launch_bounds__(512, 2)
void k_sweep(const unsigned short* __restrict__ tb, const unsigned short* __restrict__ rb,
             const int* __restrict__ counts, const unsigned* __restrict__ mbits_in,
             unsigned long long* __restrict__ packed1, unsigned* __restrict__ mbits_out,
             unsigned long long* __restrict__ Ssum)
{
    __shared__ uint4 bs[1024];           // 16 KB: 128 rows x 8 chunks of 16B
    const int p0 = blockIdx.x * RROWS, q0 = blockIdx.y * QCHUNK;
    const int t  = threadIdx.x;
    const int w  = t >> 6, l = t & 63;   // w in [0,8)
    const int l15 = l & 15, lg = l >> 4;

    // A fragments: issue global loads first so they overlap the staging
    bf16x8 afr[2][2];
#pragma unroll
    for (int mt = 0; mt < 2; ++mt)
#pragma unroll
        for (int ks = 0; ks < 2; ++ks)
            afr[mt][ks] = *(const bf16x8*)(tb + (p0 + w * 32 + mt * 16 + l15) * KP + ks * 32 + lg * 8);

    // ---- stage B tile: 1024 16B chunks; 2 per thread, XOR-swizzled write
    {
        const int r = t >> 2;            // 4 threads per row, 2 chunks each
        const int cbase = (t & 3) * 2;
        const uint4* src = (const uint4*)(rb + (q0 + r) * KP);
#pragma unroll
        for (int i = 0; i < 2; ++i) {
            int c = cbase + i;
            bs[r * 8 + (c ^ (r & 7))] = src[c];
        }
    }
    __syncthreads();

    f32x4 acc[2][8];
#pragma unroll
    for (int mt = 0; mt < 2; ++mt)
#pragma unroll
        for (int qt = 0; qt < 8; ++qt) acc[mt][qt] = (f32x4){0.f, 0.f, 0.f, 0.f};

#pragma unroll
    for (int qt = 0; qt < 8; ++qt) {
        const int row = qt * 16 + l15;
        bf16x8 b0 = *(const bf16x8*)&bs[row * 8 + ((0 + lg) ^ (row & 7))];
        bf16x8 b1 = *(const bf16x8*)&bs[row * 8 + ((4 + lg) ^ (row & 7))];
#pragma unroll
        for (int mt = 0; mt < 2; ++mt) {
            acc[mt][qt] = __builtin_amdgcn_mfma_f32_16x16x32_bf16(afr[mt][0], b0, acc[mt][qt], 0, 0, 0);
            acc[mt][qt] = __builtin_amdgcn_mfma_f32_16x16x32_bf16(afr[mt][1], b1, acc[mt][qt], 0, 0, 0);
        }
    }

    float osv[8];
    if (MODE >= 2) {
#pragma unroll
        for (int qt = 0; qt < 8; ++qt) osv[qt] = (float)counts[q0 + qt * 16 + l15] * LOCC;
    }

#pragma unroll
    for (int mt = 0; mt < 2; ++mt) {
#pragma unroll
        for (int r = 0; r < 4; ++r) {
            int p = p0 + w * 32 + mt * 16 + lg * 4 + r;
            float rinv = 0.f;
            if (MODE == 3) rinv = 1.0f / (__uint_as_float(mbits_in[p]) + EPSF);

            float bv = 1e30f; int bi = 0; float s = 0.f;
#pragma unroll
            for (int qt = 0; qt < 8; ++qt) {    // qt ascending -> q ascending per lane
                float d = fmaxf((1.0f - acc[mt][qt][r]) * 0.5f, 0.0f);
                if (MODE >= 2) d += osv[qt];
                if (MODE == 1) {
                    bool upd = d < bv;          // strict <: first occurrence wins
                    bi = upd ? (q0 + qt * 16 + l15) : bi;
                    bv = upd ? d : bv;
                } else if (MODE == 2) {
                    bv = fminf(bv, d);
                } else {
                    s += __expf((1.0f - d * rinv) * HWT);
                }
            }

            // reduce across the 16 lanes of this row group (masks 1,2,4,8)
            if (MODE == 1) {
                // packed (value,index) lexicographic min: d >= 0 so f32 bits
                // are order-preserving; ties -> smaller q.
                unsigned long long enc =
                    ((unsigned long long)__float_as_uint(bv) << 32) | (unsigned)bi;
#pragma unroll
                for (int m = 1; m < 16; m <<= 1) {
                    unsigned long long o = __shfl_xor(enc, m, 64);
                    enc = (o < enc) ? o : enc;
                }
                if (l15 == 0) atomicMin(&packed1[p], enc);
            } else if (MODE == 2) {
#pragma unroll
                for (int m = 1; m < 16; m <<= 1) bv = fminf(bv, __shfl_xor(bv, m, 64));
                if (l15 == 0) atomicMin(&mbits_out[p], __float_as_uint(bv));
            } else {
#pragma unroll
                for (int m = 1; m < 16; m <<= 1) s += __shfl_xor(s, m, 64);
                if (l15 == 0) {
                    // exact: (double)s * 2^40 is exact (s <= 128 -> < 2^47)
                    double sd = (double)s * FXSCALE + 0.5;
                    atomicAdd(&Ssum[p], (unsigned long long)sd);
                }
            }
        }
    }
}

// =====================================================================
// 4) histogram (tiny dedicated kernel: boundary IS the global sync;
//    every fused variant -- fence/serial-tail/per-block-scan/finisher --
//    measured slower in R1/R3/R4/R6)
// =====================================================================
__global__ void k_hist(const unsigned long long* __restrict__ packed1,
                       int* __restrict__ counts)
{
    int p = blockIdx.x * blockDim.x + threadIdx.x;
    if (p < P) atomicAdd(&counts[(unsigned)(packed1[p] & 0xffffffffULL)], 1);
}

// =====================================================================
// 5) epilogue: per-row -log(CX), block partials, last block finishes
//    (deterministic: last block sums the 50 partials in index order)
// =====================================================================
__global__ void k_loss(const unsigned long long* __restrict__ Ssum,
                       const unsigned* __restrict__ mbits,
                       float* __restrict__ partial, int* __restrict__ ticket,
                       float* __restrict__ out)
{
    int b = blockIdx.x, t = threadIdx.x;   // 50 blocks x 128 threads
    int p = b * 128 + t;
    float s = (float)((double)Ssum[p] * (1.0 / FXSCALE));
    float m = __uint_as_float(mbits[p]);
    float lw = (1.0f - m / (m + EPSF)) * HWT;   // log of max weight
    float v = logf(s) - lw;                      // -log(CX)
    __shared__ float red[128];
    red[t] = v; __syncthreads();
    for (int w = 64; w > 0; w >>= 1) { if (t < w) red[t] += red[t + w]; __syncthreads(); }

    __shared__ int lastblk;
    if (t == 0) {
        atomicExch(&partial[b], red[0]);   // device-scope write (coherent point)
        __threadfence();                   // 1 thread x 50 blocks: noise
        lastblk = (atomicAdd(ticket, 1) == CSPLIT - 1);
    }
    __syncthreads();
    if (lastblk && t < 64) {
        float x = (t < CSPLIT) ? atomicAdd(&partial[t], 0.0f) : 0.f;  // atomic read
#pragma unroll
        for (int mm = 32; mm > 0; mm >>= 1) x += __shfl_down(x, mm, 64);
        if (t == 0) out[0] = x * (1.0f / (float)P);
    }
}

// =====================================================================
extern "C" void kernel_launch(void* const* d_in, const int* in_sizes, int n_in,
                              void* d_out, int out_size, void* d_ws, size_t ws_size,
                              hipStream_t stream)
{
    const float* tf  = (const float*)d_in[0];
    const float* rf  = (const float*)d_in[1];
    const float* tfd = (const float*)d_in[2];
    const float* rfd = (const float*)d_in[3];
    float* out = (float*)d_out;

    float* ws = (float*)d_ws;
    float* ypart = ws;                                       // K*25 = 1225 f
    unsigned short* tb = (unsigned short*)(ws + 2048);       // P*KP bf16 = 204800 f
    unsigned short* rb = (unsigned short*)(ws + 206848);     // P*KP bf16 = 204800 f
    unsigned long long* packed1 = (unsigned long long*)(ws + 411648); // P u64 = 12800 f
    unsigned long long* Ssum    = (unsigned long long*)(ws + 424448); // P u64 = 12800 f
    unsigned* mbits   = (unsigned*)(ws + 437248);            // P
    int*      counts  = (int*)(ws + 443648);                 // P
    float*    partial = ws + 450048;                         // 64
    int*      ticket  = (int*)(ws + 450112);                 // 1
    // total ~450113 floats ~= 1.8 MB

    // 7 kernels (R2 structure): prep | normpack | sweep1 | hist | sweep2 | sweep3 | loss
    k_prep<<<K * P / 256, 256, 0, stream>>>(rf, rfd, ypart, packed1, counts, mbits, Ssum, ticket);
    k_normpack<<<(2 * P + 255) / 256, 256, 0, stream>>>(tf, rf, tfd, rfd, ypart, tb, rb);

    dim3 g(P / RROWS, CSPLIT);   // (25, 50) = 1250 blocks, 8 waves each
    k_sweep<1><<<g, 512, 0, stream>>>(tb, rb, nullptr, nullptr, packed1, nullptr, nullptr);
    k_hist<<<(P + 255) / 256, 256, 0, stream>>>(packed1, counts);
    k_sweep<2><<<g, 512, 0, stream>>>(tb, rb, counts, nullptr, nullptr, mbits, nullptr);
    k_sweep<3><<<g, 512, 0, stream>>>(tb, rb, counts, mbits, nullptr, nullptr, Ssum);

    k_loss<<<CSPLIT, 128, 0, stream>>>(Ssum, mbits, partial, ticket, out);
}

// Round 8
// 73.573 us; speedup vs baseline: 1.3124x; 1.0029x over previous
//
#include <hip/hip_runtime.h>
#include <math.h>

// ---------------- problem constants ----------------
#define P      6400      // SAMPLE*SAMPLE patches per image
#define K      49        // PATCH*PATCH channels (C=1)
#define KP     64        // K padded to MFMA granularity (pad channels are 0)
#define FH     169       // patch-grid H = W = (512-7)/3+1
#define IMG    512
#define EPSF   2.220446049250313e-16f
#define HWT    2.0f      // H_WEIGHT
#define LOCC   0.05f     // LAMBDA_OCC

// ---------------- sweep tiling ----------------
#define CSPLIT 50
#define QCHUNK  (P / CSPLIT)          // 128 columns per block
#define RROWS   256                   // rows per block (8 waves x 32)
#define FXSCALE 1099511627776.0       // 2^40 fixed-point scale

typedef __attribute__((ext_vector_type(8))) short bf16x8;  // 8 bf16 = 4 VGPR
typedef __attribute__((ext_vector_type(4))) float f32x4;

__device__ inline unsigned bfbits(float x)   // f32 -> bf16 bits, RNE
{
    unsigned u = __float_as_uint(x);
    return (u + 0x7FFFu + ((u >> 16) & 1u)) >> 16;
}

// =====================================================================
// 1) k_prep: init atomic buffers + ticket + refer channel-mean partials
//    grid = K*P/256 = 1225 blocks; each block lies in one c slice.
// =====================================================================
__global__ void k_prep(const float* __restrict__ rf, const float* __restrict__ rfield,
                       float* __restrict__ ypart,
                       unsigned long long* __restrict__ packed1,
                       int* __restrict__ counts, unsigned* __restrict__ mbits,
                       unsigned long long* __restrict__ Ssum,
                       int* __restrict__ ticket)
{
    int t = threadIdx.x;
    int gid = blockIdx.x * 256 + t;

    if (gid < P) {
        packed1[gid] = 0xFFFFFFFFFFFFFFFFULL;
        counts[gid]  = 0;
        mbits[gid]   = 0xFFFFFFFFu;
        Ssum[gid]    = 0ULL;
    }
    if (gid == 0) ticket[0] = 0;

    // ---- refer channel-mean partials
    int c = gid / P;
    int p = gid - c * P;             // block fully inside one c (P % 256 == 0)
    float fx = rfield[p * 2 + 0];
    float fy = rfield[p * 2 + 1];
    float gx = fx * 2.0f - 1.0f;
    float gy = fy * 2.0f - 1.0f;
    int ix = (int)rintf(((gx + 1.0f) * (float)FH - 1.0f) * 0.5f);
    int iy = (int)rintf(((gy + 1.0f) * (float)FH - 1.0f) * 0.5f);
    ix = min(max(ix, 0), FH - 1);
    iy = min(max(iy, 0), FH - 1);
    int ky = c / 7, kx = c - ky * 7;
    float v = rf[(iy * 3 + ky) * IMG + (ix * 3 + kx)];

    float s = v;
#pragma unroll
    for (int m = 1; m < 64; m <<= 1) s += __shfl_xor(s, m, 64);
    __shared__ float acc4[4];
    int l = t & 63, w = t >> 6;
    if (l == 0) acc4[w] = s;
    __syncthreads();
    if (t == 0) ypart[c * 25 + (p >> 8)] = acc4[0] + acc4[1] + acc4[2] + acc4[3];
}

// =====================================================================
// 2) mean-subtract + L2-normalize + pack to bf16, TRANSPOSED [p][64]
//    (R2-verbatim: 256-thread blocks, direct image gather)
// =====================================================================
__global__ void k_normpack(const float* __restrict__ tf, const float* __restrict__ rf,
                           const float* __restrict__ tfield, const float* __restrict__ rfield,
                           const float* __restrict__ ypart,
                           unsigned short* __restrict__ tb, unsigned short* __restrict__ rb)
{
    __shared__ float ym[K];
    int t = threadIdx.x;
    if (t < K) {
        float s = 0.f;
#pragma unroll
        for (int i = 0; i < 25; ++i) s += ypart[t * 25 + i];
        ym[t] = s * (1.0f / (float)P);
    }
    __syncthreads();

    int gid = blockIdx.x * 256 + t;      // grid = 2P/256 = 50 blocks
    int sel = gid >= P;
    int p = sel ? gid - P : gid;
    const float* field = sel ? rfield : tfield;
    const float* feat  = sel ? rf : tf;
    unsigned short* ob = sel ? rb : tb;

    float fx = field[p * 2 + 0];
    float fy = field[p * 2 + 1];
    float gx = fx * 2.0f - 1.0f;
    float gy = fy * 2.0f - 1.0f;
    int ix = (int)rintf(((gx + 1.0f) * (float)FH - 1.0f) * 0.5f);
    int iy = (int)rintf(((gy + 1.0f) * (float)FH - 1.0f) * 0.5f);
    ix = min(max(ix, 0), FH - 1);
    iy = min(max(iy, 0), FH - 1);
    const float* base = feat + (iy * 3) * IMG + ix * 3;

    float v[K];
#pragma unroll
    for (int ky = 0; ky < 7; ++ky)
#pragma unroll
        for (int kx = 0; kx < 7; ++kx)
            v[ky * 7 + kx] = base[ky * IMG + kx];

    float ss = 0.f;
#pragma unroll
    for (int c = 0; c < K; ++c) {
        float x = v[c] - ym[c];
        v[c] = x;
        ss += x * x;
    }
    float rn = 1.0f / (sqrtf(ss) + EPSF);

    unsigned wbuf[KP / 2];
#pragma unroll
    for (int i = 0; i < KP / 2; ++i) {
        int c0 = 2 * i, c1 = 2 * i + 1;
        float x0 = (c0 < K) ? v[c0] * rn : 0.f;
        float x1 = (c1 < K) ? v[c1] * rn : 0.f;
        wbuf[i] = (bfbits(x1) << 16) | bfbits(x0);
    }
    uint4* o = (uint4*)(ob + p * KP);    // p*128 bytes: 16B aligned
#pragma unroll
    for (int i = 0; i < KP / 8; ++i)
        o[i] = make_uint4(wbuf[4 * i], wbuf[4 * i + 1], wbuf[4 * i + 2], wbuf[4 * i + 3]);
}

// =====================================================================
// 3) MFMA sim sweeps. 8 waves; 256(p) x 128(q) tile; K=64 (2 steps).
//    __launch_bounds__(512, 4): 4 waves/EU -> 2 blocks/CU co-resident
//    = 16 waves/CU (same occupancy as the proven R2 config; R7's (512,2)
//    was 1 block/CU = half occupancy and regressed +1.5us/sweep).
//    8 waves share one staged B tile -> staging events and B L2 traffic
//    halve vs the 4-wave version. B tile XOR-swizzled in 16B chunks
//    (conflict-free, measured 0 conflicts).
//    A/B frag: lane l holds 8 contiguous k at row l&15, k0=(l>>4)*8
//    C/D:      col=l&15, row=(l>>4)*4+reg
//    MODE 1: per-row argmin of d0 (first-occurrence ties) -> atomicMin u64
//    MODE 2: per-row min of d0 + counts[q]*LOCC           -> atomicMin u32
//    MODE 3: per-row sum exp((1-d/(m+EPS))*H) -> exact fixed-point
//            atomicAdd(Ssum)  (integer adds commute -> deterministic)
// =====================================================================
template<int MODE>
__global__ __launch_bounds__(512, 4)
void k_sweep(const unsigned short* __restrict__ tb, const unsigned short* __restrict__ rb,
             const int* __restrict__ counts, const unsigned* __restrict__ mbits_in,
             unsigned long long* __restrict__ packed1, unsigned* __restrict__ mbits_out,
             unsigned long long* __restrict__ Ssum)
{
    __shared__ uint4 bs[1024];           // 16 KB: 128 rows x 8 chunks of 16B
    const int p0 = blockIdx.x * RROWS, q0 = blockIdx.y * QCHUNK;
    const int t  = threadIdx.x;
    const int w  = t >> 6, l = t & 63;   // w in [0,8)
    const int l15 = l & 15, lg = l >> 4;

    // A fragments: issue global loads first so they overlap the staging
    bf16x8 afr[2][2];
#pragma unroll
    for (int mt = 0; mt < 2; ++mt)
#pragma unroll
        for (int ks = 0; ks < 2; ++ks)
            afr[mt][ks] = *(const bf16x8*)(tb + (p0 + w * 32 + mt * 16 + l15) * KP + ks * 32 + lg * 8);

    // ---- stage B tile: 1024 16B chunks; 2 per thread, XOR-swizzled write
    {
        const int r = t >> 2;            // 4 threads per row, 2 chunks each
        const int cbase = (t & 3) * 2;
        const uint4* src = (const uint4*)(rb + (q0 + r) * KP);
#pragma unroll
        for (int i = 0; i < 2; ++i) {
            int c = cbase + i;
            bs[r * 8 + (c ^ (r & 7))] = src[c];
        }
    }
    __syncthreads();

    f32x4 acc[2][8];
#pragma unroll
    for (int mt = 0; mt < 2; ++mt)
#pragma unroll
        for (int qt = 0; qt < 8; ++qt) acc[mt][qt] = (f32x4){0.f, 0.f, 0.f, 0.f};

#pragma unroll
    for (int qt = 0; qt < 8; ++qt) {
        const int row = qt * 16 + l15;
        bf16x8 b0 = *(const bf16x8*)&bs[row * 8 + ((0 + lg) ^ (row & 7))];
        bf16x8 b1 = *(const bf16x8*)&bs[row * 8 + ((4 + lg) ^ (row & 7))];
#pragma unroll
        for (int mt = 0; mt < 2; ++mt) {
            acc[mt][qt] = __builtin_amdgcn_mfma_f32_16x16x32_bf16(afr[mt][0], b0, acc[mt][qt], 0, 0, 0);
            acc[mt][qt] = __builtin_amdgcn_mfma_f32_16x16x32_bf16(afr[mt][1], b1, acc[mt][qt], 0, 0, 0);
        }
    }

    float osv[8];
    if (MODE >= 2) {
#pragma unroll
        for (int qt = 0; qt < 8; ++qt) osv[qt] = (float)counts[q0 + qt * 16 + l15] * LOCC;
    }

#pragma unroll
    for (int mt = 0; mt < 2; ++mt) {
#pragma unroll
        for (int r = 0; r < 4; ++r) {
            int p = p0 + w * 32 + mt * 16 + lg * 4 + r;
            float rinv = 0.f;
            if (MODE == 3) rinv = 1.0f / (__uint_as_float(mbits_in[p]) + EPSF);

            float bv = 1e30f; int bi = 0; float s = 0.f;
#pragma unroll
            for (int qt = 0; qt < 8; ++qt) {    // qt ascending -> q ascending per lane
                float d = fmaxf((1.0f - acc[mt][qt][r]) * 0.5f, 0.0f);
                if (MODE >= 2) d += osv[qt];
                if (MODE == 1) {
                    bool upd = d < bv;          // strict <: first occurrence wins
                    bi = upd ? (q0 + qt * 16 + l15) : bi;
                    bv = upd ? d : bv;
                } else if (MODE == 2) {
                    bv = fminf(bv, d);
                } else {
                    s += __expf((1.0f - d * rinv) * HWT);
                }
            }

            // reduce across the 16 lanes of this row group (masks 1,2,4,8)
            if (MODE == 1) {
                // packed (value,index) lexicographic min: d >= 0 so f32 bits
                // are order-preserving; ties -> smaller q.
                unsigned long long enc =
                    ((unsigned long long)__float_as_uint(bv) << 32) | (unsigned)bi;
#pragma unroll
                for (int m = 1; m < 16; m <<= 1) {
                    unsigned long long o = __shfl_xor(enc, m, 64);
                    enc = (o < enc) ? o : enc;
                }
                if (l15 == 0) atomicMin(&packed1[p], enc);
            } else if (MODE == 2) {
#pragma unroll
                for (int m = 1; m < 16; m <<= 1) bv = fminf(bv, __shfl_xor(bv, m, 64));
                if (l15 == 0) atomicMin(&mbits_out[p], __float_as_uint(bv));
            } else {
#pragma unroll
                for (int m = 1; m < 16; m <<= 1) s += __shfl_xor(s, m, 64);
                if (l15 == 0) {
                    // exact: (double)s * 2^40 is exact (s <= 128 -> < 2^47)
                    double sd = (double)s * FXSCALE + 0.5;
                    atomicAdd(&Ssum[p], (unsigned long long)sd);
                }
            }
        }
    }
}

// =====================================================================
// 4) histogram (tiny dedicated kernel: boundary IS the global sync;
//    every fused variant -- fence/serial-tail/per-block-scan/finisher --
//    measured slower in R1/R3/R4/R6)
// =====================================================================
__global__ void k_hist(const unsigned long long* __restrict__ packed1,
                       int* __restrict__ counts)
{
    int p = blockIdx.x * blockDim.x + threadIdx.x;
    if (p < P) atomicAdd(&counts[(unsigned)(packed1[p] & 0xffffffffULL)], 1);
}

// =====================================================================
// 5) epilogue: per-row -log(CX), block partials, last block finishes
//    (deterministic: last block sums the 50 partials in index order)
// =====================================================================
__global__ void k_loss(const unsigned long long* __restrict__ Ssum,
                       const unsigned* __restrict__ mbits,
                       float* __restrict__ partial, int* __restrict__ ticket,
                       float* __restrict__ out)
{
    int b = blockIdx.x, t = threadIdx.x;   // 50 blocks x 128 threads
    int p = b * 128 + t;
    float s = (float)((double)Ssum[p] * (1.0 / FXSCALE));
    float m = __uint_as_float(mbits[p]);
    float lw = (1.0f - m / (m + EPSF)) * HWT;   // log of max weight
    float v = logf(s) - lw;                      // -log(CX)
    __shared__ float red[128];
    red[t] = v; __syncthreads();
    for (int w = 64; w > 0; w >>= 1) { if (t < w) red[t] += red[t + w]; __syncthreads(); }

    __shared__ int lastblk;
    if (t == 0) {
        atomicExch(&partial[b], red[0]);   // device-scope write (coherent point)
        __threadfence();                   // 1 thread x 50 blocks: noise
        lastblk = (atomicAdd(ticket, 1) == CSPLIT - 1);
    }
    __syncthreads();
    if (lastblk && t < 64) {
        float x = (t < CSPLIT) ? atomicAdd(&partial[t], 0.0f) : 0.f;  // atomic read
#pragma unroll
        for (int mm = 32; mm > 0; mm >>= 1) x += __shfl_down(x, mm, 64);
        if (t == 0) out[0] = x * (1.0f / (float)P);
    }
}

// =====================================================================
extern "C" void kernel_launch(void* const* d_in, const int* in_sizes, int n_in,
                              void* d_out, int out_size, void* d_ws, size_t ws_size,
                              hipStream_t stream)
{
    const float* tf  = (const float*)d_in[0];
    const float* rf  = (const float*)d_in[1];
    const float* tfd = (const float*)d_in[2];
    const float* rfd = (const float*)d_in[3];
    float* out = (float*)d_out;

    float* ws = (float*)d_ws;
    float* ypart = ws;                                       // K*25 = 1225 f
    unsigned short* tb = (unsigned short*)(ws + 2048);       // P*KP bf16 = 204800 f
    unsigned short* rb = (unsigned short*)(ws + 206848);     // P*KP bf16 = 204800 f
    unsigned long long* packed1 = (unsigned long long*)(ws + 411648); // P u64 = 12800 f
    unsigned long long* Ssum    = (unsigned long long*)(ws + 424448); // P u64 = 12800 f
    unsigned* mbits   = (unsigned*)(ws + 437248);            // P
    int*      counts  = (int*)(ws + 443648);                 // P
    float*    partial = ws + 450048;                         // 64
    int*      ticket  = (int*)(ws + 450112);                 // 1
    // total ~450113 floats ~= 1.8 MB

    // 7 kernels (R2 structure): prep | normpack | sweep1 | hist | sweep2 | sweep3 | loss
    k_prep<<<K * P / 256, 256, 0, stream>>>(rf, rfd, ypart, packed1, counts, mbits, Ssum, ticket);
    k_normpack<<<(2 * P + 255) / 256, 256, 0, stream>>>(tf, rf, tfd, rfd, ypart, tb, rb);

    dim3 g(P / RROWS, CSPLIT);   // (25, 50) = 1250 blocks, 8 waves each
    k_sweep<1><<<g, 512, 0, stream>>>(tb, rb, nullptr, nullptr, packed1, nullptr, nullptr);
    k_hist<<<(P + 255) / 256, 256, 0, stream>>>(packed1, counts);
    k_sweep<2><<<g, 512, 0, stream>>>(tb, rb, counts, nullptr, nullptr, mbits, nullptr);
    k_sweep<3><<<g, 512, 0, stream>>>(tb, rb, counts, mbits, nullptr, nullptr, Ssum);

    k_loss<<<CSPLIT, 128, 0, stream>>>(Ssum, mbits, partial, ticket, out);
}

// Round 9
// 69.449 us; speedup vs baseline: 1.3903x; 1.0594x over previous
//
#include <hip/hip_runtime.h>
#include <math.h>

// ---------------- problem constants ----------------
#define P      6400      // SAMPLE*SAMPLE patches per image
#define K      49        // PATCH*PATCH channels (C=1)
#define KP     64        // K padded to MFMA granularity (pad channels are 0)
#define FH     169       // patch-grid H = W = (512-7)/3+1
#define IMG    512
#define EPSF   2.220446049250313e-16f
#define HWT    2.0f      // H_WEIGHT
#define LOCC   0.05f     // LAMBDA_OCC

// ---------------- sweep tiling ----------------
#define CSPLIT 50
#define QCHUNK (P / CSPLIT)   // 128 columns per block; 128 rows per block

typedef __attribute__((ext_vector_type(8))) short bf16x8;  // 8 bf16 = 4 VGPR
typedef __attribute__((ext_vector_type(4))) float f32x4;

__device__ inline unsigned bfbits(float x)   // f32 -> bf16 bits, RNE
{
    unsigned u = __float_as_uint(x);
    return (u + 0x7FFFu + ((u >> 16) & 1u)) >> 16;
}

// =====================================================================
// 1) k_prep: (a) init atomic/hist buffers + tickets
//            (b) refer-patch gather -> per-(c, 256-block) partial sums
//    grid = K*P/256 = 1225 blocks; each block lies in one c slice.
// =====================================================================
__global__ void k_prep(const float* __restrict__ rf, const float* __restrict__ rfield,
                       float* __restrict__ ypart,
                       unsigned long long* __restrict__ packed1,
                       int* __restrict__ counts, unsigned* __restrict__ mbits,
                       int* __restrict__ tickets)
{
    int t = threadIdx.x;
    int gid = blockIdx.x * 256 + t;

    // ---- init section (independent buffers, consumed by later kernels)
    if (gid < P) {
        packed1[gid] = 0xFFFFFFFFFFFFFFFFULL;
        counts[gid]  = 0;
        mbits[gid]   = 0xFFFFFFFFu;
    }
    if (gid < 2) tickets[gid] = 0;

    // ---- refer channel-mean partials
    int c = gid / P;
    int p = gid - c * P;             // block fully inside one c (P % 256 == 0)
    float fx = rfield[p * 2 + 0];
    float fy = rfield[p * 2 + 1];
    float gx = fx * 2.0f - 1.0f;
    float gy = fy * 2.0f - 1.0f;
    int ix = (int)rintf(((gx + 1.0f) * (float)FH - 1.0f) * 0.5f);
    int iy = (int)rintf(((gy + 1.0f) * (float)FH - 1.0f) * 0.5f);
    ix = min(max(ix, 0), FH - 1);
    iy = min(max(iy, 0), FH - 1);
    int ky = c / 7, kx = c - ky * 7;
    float v = rf[(iy * 3 + ky) * IMG + (ix * 3 + kx)];

    // wave shuffle reduce (64 lanes), then 4 waves via LDS
    float s = v;
#pragma unroll
    for (int m = 1; m < 64; m <<= 1) s += __shfl_xor(s, m, 64);
    __shared__ float acc4[4];
    int l = t & 63, w = t >> 6;
    if (l == 0) acc4[w] = s;
    __syncthreads();
    if (t == 0) ypart[c * 25 + (p >> 8)] = acc4[0] + acc4[1] + acc4[2] + acc4[3];
}

// =====================================================================
// 2) mean-subtract + L2-normalize + pack to bf16, TRANSPOSED [p][64]
//    Gathers the 49 patch values straight from the image into registers.
// =====================================================================
__global__ void k_normpack(const float* __restrict__ tf, const float* __restrict__ rf,
                           const float* __restrict__ tfield, const float* __restrict__ rfield,
                           const float* __restrict__ ypart,
                           unsigned short* __restrict__ tb, unsigned short* __restrict__ rb)
{
    __shared__ float ym[K];
    int t = threadIdx.x;
    if (t < K) {
        float s = 0.f;
#pragma unroll
        for (int i = 0; i < 25; ++i) s += ypart[t * 25 + i];
        ym[t] = s * (1.0f / (float)P);
    }
    __syncthreads();

    int gid = blockIdx.x * 256 + t;      // grid = 2P/256 = 50 blocks
    int sel = gid >= P;
    int p = sel ? gid - P : gid;
    const float* field = sel ? rfield : tfield;
    const float* feat  = sel ? rf : tf;
    unsigned short* ob = sel ? rb : tb;

    float fx = field[p * 2 + 0];
    float fy = field[p * 2 + 1];
    float gx = fx * 2.0f - 1.0f;
    float gy = fy * 2.0f - 1.0f;
    int ix = (int)rintf(((gx + 1.0f) * (float)FH - 1.0f) * 0.5f);
    int iy = (int)rintf(((gy + 1.0f) * (float)FH - 1.0f) * 0.5f);
    ix = min(max(ix, 0), FH - 1);
    iy = min(max(iy, 0), FH - 1);
    const float* base = feat + (iy * 3) * IMG + ix * 3;

    float v[K];
#pragma unroll
    for (int ky = 0; ky < 7; ++ky)
#pragma unroll
        for (int kx = 0; kx < 7; ++kx)
            v[ky * 7 + kx] = base[ky * IMG + kx];

    float ss = 0.f;
#pragma unroll
    for (int c = 0; c < K; ++c) {
        float x = v[c] - ym[c];
        v[c] = x;
        ss += x * x;
    }
    float rn = 1.0f / (sqrtf(ss) + EPSF);

    unsigned wbuf[KP / 2];
#pragma unroll
    for (int i = 0; i < KP / 2; ++i) {
        int c0 = 2 * i, c1 = 2 * i + 1;
        float x0 = (c0 < K) ? v[c0] * rn : 0.f;
        float x1 = (c1 < K) ? v[c1] * rn : 0.f;
        wbuf[i] = (bfbits(x1) << 16) | bfbits(x0);
    }
    uint4* o = (uint4*)(ob + p * KP);    // p*128 bytes: 16B aligned
#pragma unroll
    for (int i = 0; i < KP / 8; ++i)
        o[i] = make_uint4(wbuf[4 * i], wbuf[4 * i + 1], wbuf[4 * i + 2], wbuf[4 * i + 3]);
}

// =====================================================================
// 3) MFMA sim sweeps. block = 4 waves; 128(p) x 128(q) tile; K=64 (2 steps).
//    B tile (shared by all 4 waves) staged once in LDS, XOR-swizzled in
//    16B chunks: lds_chunk(r, c^(r&7)) = glb_chunk(r, c). Read side uses
//    the same involution -> 8 distinct bank-quads per wave access
//    (the ds_read_b128 minimum; conflict-free, measured 0 conflicts).
//    A/B frag: lane l holds 8 contiguous k at row l&15, k0=(l>>4)*8
//    C/D:      col=l&15, row=(l>>4)*4+reg
//    MODE 1: per-row argmin of d0 (first-occurrence ties) -> atomicMin u64
//    MODE 2: per-row min of d0 + cnt[q]*LOCC              -> atomicMin u32
//    MODE 3: per-row sum exp((1 - d/(m+EPS))*H)           -> Spart
// =====================================================================
template<int MODE>
__global__ __launch_bounds__(256, 4)
void k_sweep(const unsigned short* __restrict__ tb, const unsigned short* __restrict__ rb,
             const int* __restrict__ counts, const unsigned* __restrict__ mbits_in,
             unsigned long long* __restrict__ packed1, unsigned* __restrict__ mbits_out,
             float* __restrict__ Spart)
{
    __shared__ uint4 bs[1024];           // 16 KB: 128 rows x 8 chunks of 16B
    const int p0 = blockIdx.x * 128, q0 = blockIdx.y * QCHUNK;
    const int t  = threadIdx.x;
    const int w  = t >> 6, l = t & 63;
    const int l15 = l & 15, lg = l >> 4;

    // A fragments: issue global loads first so they overlap the staging
    bf16x8 afr[2][2];
#pragma unroll
    for (int mt = 0; mt < 2; ++mt)
#pragma unroll
        for (int ks = 0; ks < 2; ++ks)
            afr[mt][ks] = *(const bf16x8*)(tb + (p0 + w * 32 + mt * 16 + l15) * KP + ks * 32 + lg * 8);

    // ---- stage B tile: 1024 16B chunks; 4 per thread, XOR-swizzled write
    {
        const int r = t >> 1;            // 2 threads per row, 4 chunks each
        const int cbase = (t & 1) * 4;
        const uint4* src = (const uint4*)(rb + (q0 + r) * KP);
#pragma unroll
        for (int i = 0; i < 4; ++i) {
            int c = cbase + i;
            bs[r * 8 + (c ^ (r & 7))] = src[c];
        }
    }
    __syncthreads();

    f32x4 acc[2][8];
#pragma unroll
    for (int mt = 0; mt < 2; ++mt)
#pragma unroll
        for (int qt = 0; qt < 8; ++qt) acc[mt][qt] = (f32x4){0.f, 0.f, 0.f, 0.f};

#pragma unroll
    for (int qt = 0; qt < 8; ++qt) {
        const int row = qt * 16 + l15;
        bf16x8 b0 = *(const bf16x8*)&bs[row * 8 + ((0 + lg) ^ (row & 7))];
        bf16x8 b1 = *(const bf16x8*)&bs[row * 8 + ((4 + lg) ^ (row & 7))];
#pragma unroll
        for (int mt = 0; mt < 2; ++mt) {
            acc[mt][qt] = __builtin_amdgcn_mfma_f32_16x16x32_bf16(afr[mt][0], b0, acc[mt][qt], 0, 0, 0);
            acc[mt][qt] = __builtin_amdgcn_mfma_f32_16x16x32_bf16(afr[mt][1], b1, acc[mt][qt], 0, 0, 0);
        }
    }

    float osv[8];
    if (MODE >= 2) {
#pragma unroll
        for (int qt = 0; qt < 8; ++qt) osv[qt] = (float)counts[q0 + qt * 16 + l15] * LOCC;
    }

#pragma unroll
    for (int mt = 0; mt < 2; ++mt) {
#pragma unroll
        for (int r = 0; r < 4; ++r) {
            int p = p0 + w * 32 + mt * 16 + lg * 4 + r;
            float rinv = 0.f;
            if (MODE == 3) rinv = 1.0f / (__uint_as_float(mbits_in[p]) + EPSF);

            float bv = 1e30f; int bi = 0; float s = 0.f;
#pragma unroll
            for (int qt = 0; qt < 8; ++qt) {    // qt ascending -> q ascending per lane
                float d = fmaxf((1.0f - acc[mt][qt][r]) * 0.5f, 0.0f);
                if (MODE >= 2) d += osv[qt];
                if (MODE == 1) {
                    bool upd = d < bv;          // strict <: first occurrence wins
                    bi = upd ? (q0 + qt * 16 + l15) : bi;
                    bv = upd ? d : bv;
                } else if (MODE == 2) {
                    bv = fminf(bv, d);
                } else {
                    s += __expf((1.0f - d * rinv) * HWT);
                }
            }

            // reduce across the 16 lanes of this row group (masks 1,2,4,8)
            if (MODE == 1) {
                // packed (value,index) lexicographic min: d >= 0 so f32 bits
                // are order-preserving; ties -> smaller q.
                unsigned long long enc =
                    ((unsigned long long)__float_as_uint(bv) << 32) | (unsigned)bi;
#pragma unroll
                for (int m = 1; m < 16; m <<= 1) {
                    unsigned long long o = __shfl_xor(enc, m, 64);
                    enc = (o < enc) ? o : enc;
                }
                if (l15 == 0) atomicMin(&packed1[p], enc);
            } else if (MODE == 2) {
#pragma unroll
                for (int m = 1; m < 16; m <<= 1) bv = fminf(bv, __shfl_xor(bv, m, 64));
                if (l15 == 0) atomicMin(&mbits_out[p], __float_as_uint(bv));
            } else {
#pragma unroll
                for (int m = 1; m < 16; m <<= 1) s += __shfl_xor(s, m, 64);
                if (l15 == 0) Spart[blockIdx.y * P + p] = s;
            }
        }
    }
}

// =====================================================================
// 4) histogram (separate kernel: kernel boundary provides the global
//    ordering; every fused variant -- fence/serial-tail/per-block-scan/
//    finisher-ticket -- measured slower in R1/R3/R4/R6)
// =====================================================================
__global__ void k_hist(const unsigned long long* __restrict__ packed1,
                       int* __restrict__ counts)
{
    int p = blockIdx.x * blockDim.x + threadIdx.x;
    if (p < P) atomicAdd(&counts[(unsigned)(packed1[p] & 0xffffffffULL)], 1);
}

// =====================================================================
// 5) epilogue: per-row -log(CX), block partials, last block finishes
//    (deterministic: last block sums the 50 partials in index order;
//    fence is single-thread x 50 blocks -> noise)
// =====================================================================
__global__ void k_loss(const float* __restrict__ Spart, const unsigned* __restrict__ mbits,
                       float* __restrict__ partial, int* __restrict__ ticket,
                       float* __restrict__ out)
{
    int b = blockIdx.x, t = threadIdx.x;   // 50 blocks x 128 threads
    int p = b * 128 + t;
    float s = 0.f;
#pragma unroll
    for (int cb = 0; cb < CSPLIT; ++cb) s += Spart[cb * P + p];
    float m = __uint_as_float(mbits[p]);
    float lw = (1.0f - m / (m + EPSF)) * HWT;   // log of max weight
    float v = logf(s) - lw;                      // -log(CX)
    __shared__ float red[128];
    red[t] = v; __syncthreads();
    for (int w = 64; w > 0; w >>= 1) { if (t < w) red[t] += red[t + w]; __syncthreads(); }

    __shared__ int lastblk;
    if (t == 0) {
        atomicExch(&partial[b], red[0]);   // device-scope write (coherent point)
        __threadfence();
        lastblk = (atomicAdd(ticket, 1) == CSPLIT - 1);
    }
    __syncthreads();
    if (lastblk && t < 64) {
        float x = (t < CSPLIT) ? atomicAdd(&partial[t], 0.0f) : 0.f;  // atomic read
#pragma unroll
        for (int mm = 32; mm > 0; mm >>= 1) x += __shfl_down(x, mm, 64);
        if (t == 0) out[0] = x * (1.0f / (float)P);
    }
}

// =====================================================================
extern "C" void kernel_launch(void* const* d_in, const int* in_sizes, int n_in,
                              void* d_out, int out_size, void* d_ws, size_t ws_size,
                              hipStream_t stream)
{
    const float* tf  = (const float*)d_in[0];
    const float* rf  = (const float*)d_in[1];
    const float* tfd = (const float*)d_in[2];
    const float* rfd = (const float*)d_in[3];
    float* out = (float*)d_out;

    float* ws = (float*)d_ws;
    float* ypart = ws;                                       // K*25 = 1225 f
    unsigned short* tb = (unsigned short*)(ws + 2048);       // P*KP bf16 = 204800 f
    unsigned short* rb = (unsigned short*)(ws + 206848);     // P*KP bf16 = 204800 f
    float* Spart = ws + 411648;                              // CSPLIT*P = 320000 f
    unsigned long long* packed1 = (unsigned long long*)(ws + 731648); // P u64 = 12800 f
    int*      counts  = (int*)(ws + 744448);                 // P
    unsigned* mbits   = (unsigned*)(ws + 750848);            // P
    float*    partial = ws + 757248;                         // 64
    int*      tickets = (int*)(ws + 757312);                 // 2
    // total ~757314 floats ~= 3.0 MB

    // 7 kernels: prep | normpack | sweep1 | hist | sweep2 | sweep3 | loss+final
    k_prep<<<K * P / 256, 256, 0, stream>>>(rf, rfd, ypart, packed1, counts, mbits, tickets);
    k_normpack<<<(2 * P + 255) / 256, 256, 0, stream>>>(tf, rf, tfd, rfd, ypart, tb, rb);

    dim3 g(P / 128, CSPLIT);
    k_sweep<1><<<g, 256, 0, stream>>>(tb, rb, nullptr, nullptr, packed1, nullptr, nullptr);
    k_hist<<<(P + 255) / 256, 256, 0, stream>>>(packed1, counts);
    k_sweep<2><<<g, 256, 0, stream>>>(tb, rb, counts, nullptr, nullptr, mbits, nullptr);
    k_sweep<3><<<g, 256, 0, stream>>>(tb, rb, counts, mbits, nullptr, nullptr, Spart);

    k_loss<<<CSPLIT, 128, 0, stream>>>(Spart, mbits, partial, &tickets[1], out);
}